// Round 1
// baseline (221.933 us; speedup 1.0000x reference)
//
#include <hip/hip_runtime.h>
#include <math.h>

#define NATOMS 10000
#define NEDGES 320000
#define NBINS  (NATOMS * 4)   // bin = atom*4 + species; bin a*4+3 always empty
#define RC_F 5.0f
#define PI_F 3.14159265358979323846f

// ---- workspace layout (in floats) ----
#define WS_SEMB   0         // 12 floats
#define WS_GTOT   12        // 1 int global allocation cursor
#define WS_CNT    16        // NBINS ints
#define WS_OFFS   40016     // NBINS ints (int4/atom: run starts t=0,1,2 + end)
#define WS_CURSOR 80016     // NBINS ints
#define WS_EIDX   120016    // (unused now; kept for layout stability)
#define WS_SA     440096    // NEDGES*32 floats: R[0..23] (+pad), 128B recs, POS-ordered
#define WS_SB     10680096  // NEDGES*32 floats: R[24..47], rhat (+pad), POS-ordered

// multinomial term tables (global component index 0..34)
__device__ __constant__ int   d_PWA[35] = {0, 0,0,1, 0,0,0,1,1,2, 0,0,0,0,1,1,1,2,2,3, 0,0,0,0,0,1,1,1,1,2,2,2,3,3,4};
__device__ __constant__ int   d_PWB[35] = {0, 0,1,0, 0,1,2,0,1,0, 0,1,2,3,0,1,2,0,1,0, 0,1,2,3,4,0,1,2,3,0,1,2,0,1,0};
__device__ __constant__ int   d_PWC[35] = {0, 1,0,0, 2,1,0,1,0,0, 3,2,1,0,2,1,0,1,0,0, 4,3,2,1,0,3,2,1,0,2,1,0,1,0,0};
__device__ __constant__ float d_NM[35]  = {1.f, 1.f,1.f,1.f, 1.f,2.f,1.f,2.f,2.f,1.f,
                                           1.f,3.f,3.f,1.f,3.f,6.f,3.f,3.f,3.f,1.f,
                                           1.f,4.f,6.f,4.f,1.f,4.f,12.f,12.f,4.f,6.f,12.f,6.f,4.f,4.f,1.f};
__device__ __constant__ int   d_LBLK[35]= {0, 1,1,1, 2,2,2,2,2,2, 3,3,3,3,3,3,3,3,3,3, 4,4,4,4,4,4,4,4,4,4,4,4,4,4,4};
__device__ __constant__ int   d_L6[6]   = {0,1,4,10,20,35};

__device__ __forceinline__ float siluf(float x) { return x / (1.0f + __expf(-x)); }

__device__ __forceinline__ float2 f2fma(float2 a, float2 b, float2 c) {
  return make_float2(fmaf(a.x, b.x, c.x), fmaf(a.y, b.y, c.y));
}

__device__ __forceinline__ float psel(float x, int p) {
  float x2 = x * x;
  float r = 1.0f;
  r = (p == 1) ? x : r;
  r = (p == 2) ? x2 : r;
  r = (p == 3) ? x2 * x : r;
  r = (p == 4) ? x2 * x2 : r;
  return r;
}

// ---------------- k_init ----------------
__global__ void k_init(const float* __restrict__ Ws1, const float* __restrict__ bs1,
                       const float* __restrict__ Ws2, const float* __restrict__ bs2,
                       float* __restrict__ ws)
{
  int tid = blockIdx.x * blockDim.x + threadIdx.x;
  int* cnt = (int*)(ws + WS_CNT);
  if (tid < NBINS) cnt[tid] = 0;
  if (tid == 0) *(int*)(ws + WS_GTOT) = 0;
  if (tid < 12) {
    int t = tid >> 2, s = tid & 3;
    float acc = bs2[s];
    for (int j = 0; j < 16; j++) acc += tanhf(Ws1[t * 16 + j] + bs1[j]) * Ws2[j * 4 + s];
    ws[WS_SEMB + tid] = acc;
  }
}

// ---------------- k_hist: (atom,species)-bin counts ----------------
__global__ void k_hist(const int* __restrict__ first_atom, const int* __restrict__ second_atom,
                       const int* __restrict__ species, float* __restrict__ ws)
{
  int e = blockIdx.x * blockDim.x + threadIdx.x;
  if (e < NEDGES) {
    int* cnt = (int*)(ws + WS_CNT);
    int bin = first_atom[e] * 4 + species[second_atom[e]];
    atomicAdd(&cnt[bin], 1);
  }
}

// ---------------- k_alloc: decentralized run allocation, int4 per atom ----------------
__global__ __launch_bounds__(256) void k_alloc(float* __restrict__ ws)
{
  const int4* cnt4 = (const int4*)(ws + WS_CNT);
  int4* offs4   = (int4*)(ws + WS_OFFS);
  int4* cursor4 = (int4*)(ws + WS_CURSOR);
  int* gtot = (int*)(ws + WS_GTOT);
  __shared__ int wsum[4];
  __shared__ int sbase;
  int tid = threadIdx.x;
  int lane = tid & 63, wv = tid >> 6;
  int a = blockIdx.x * 256 + tid;
  bool live = (a < NATOMS);
  int4 c = live ? cnt4[a] : make_int4(0, 0, 0, 0);
  int s = c.x + c.y + c.z + c.w;
  int inc = s;
  #pragma unroll
  for (int d = 1; d < 64; d <<= 1) {
    int v = __shfl_up(inc, d, 64);
    if (lane >= d) inc += v;
  }
  if (lane == 63) wsum[wv] = inc;
  __syncthreads();
  if (tid == 0) sbase = atomicAdd(gtot, wsum[0] + wsum[1] + wsum[2] + wsum[3]);
  __syncthreads();
  int woff = sbase;
  for (int w = 0; w < wv; w++) woff += wsum[w];
  int o0 = woff + inc - s;
  if (live) {
    int4 o;
    o.x = o0;
    o.y = o.x + c.x;
    o.z = o.y + c.y;
    o.w = o.z + c.z;
    offs4[a] = o;
    cursor4[a] = o;
  }
}

// ---------------- k_edge: packed-FMA MLP -> direct scatter-store to sorted slot ----------------
// Records are written directly at the (atom,species)-sorted position `pos`,
// so k_atom reads become contiguous streams. No LDS, no eidx.
__global__ __launch_bounds__(256) void k_edge(
    const float* __restrict__ rij, const int* __restrict__ species,
    const int* __restrict__ first_atom, const int* __restrict__ second_atom,
    const float* __restrict__ Wr1, const float* __restrict__ br1,
    const float* __restrict__ Wr2, const float* __restrict__ br2,
    float* __restrict__ ws)
{
  int e = blockIdx.x * 256 + threadIdx.x;
  int* cursor = (int*)(ws + WS_CURSOR);

  int a = first_atom[e];
  int t = species[second_atom[e]];
  int pos = atomicAdd(&cursor[a * 4 + t], 1);

  float x = rij[e * 3 + 0], y = rij[e * 3 + 1], z = rij[e * 3 + 2];
  float d = sqrtf(x * x + y * y + z * z + 1e-12f);
  float invd = 1.0f / d;

  float theta = (PI_F / RC_F) * d;
  float s1 = __sinf(theta), c1 = __cosf(theta);
  float fc = (d < RC_F) ? 0.5f * (c1 + 1.0f) : 0.0f;
  float bes[8];
  {
    float sq = sqrtf(2.0f / RC_F) * invd;
    float twoc = 2.0f * c1;
    float sp = 0.0f, sc = s1;
    #pragma unroll
    for (int k = 0; k < 8; k++) {
      bes[k] = sq * sc;
      float sn = twoc * sc - sp;
      sp = sc; sc = sn;
    }
  }

  float h1[64];
  #pragma unroll
  for (int j4 = 0; j4 < 16; j4++) {
    float2 a01 = *(const float2*)&br1[j4 * 4];
    float2 a23 = *(const float2*)&br1[j4 * 4 + 2];
    #pragma unroll
    for (int k = 0; k < 8; k++) {
      float2 b2 = make_float2(bes[k], bes[k]);
      a01 = f2fma(b2, *(const float2*)&Wr1[k * 64 + j4 * 4],     a01);
      a23 = f2fma(b2, *(const float2*)&Wr1[k * 64 + j4 * 4 + 2], a23);
    }
    h1[j4 * 4 + 0] = siluf(a01.x);
    h1[j4 * 4 + 1] = siluf(a01.y);
    h1[j4 * 4 + 2] = siluf(a23.x);
    h1[j4 * 4 + 3] = siluf(a23.y);
  }

  float* recA = ws + WS_SA + (size_t)pos * 32;
  float* recB = ws + WS_SB + (size_t)pos * 32;

  for (int j4 = 0; j4 < 6; j4++) {
    float2 a01 = *(const float2*)&br2[j4 * 4];
    float2 a23 = *(const float2*)&br2[j4 * 4 + 2];
    #pragma unroll
    for (int k = 0; k < 64; k++) {
      float2 h2 = make_float2(h1[k], h1[k]);
      a01 = f2fma(h2, *(const float2*)&Wr2[k * 48 + j4 * 4],     a01);
      a23 = f2fma(h2, *(const float2*)&Wr2[k * 48 + j4 * 4 + 2], a23);
    }
    *(float4*)(recA + j4 * 4) = make_float4(siluf(a01.x) * fc, siluf(a01.y) * fc,
                                            siluf(a23.x) * fc, siluf(a23.y) * fc);
  }

  for (int j4 = 6; j4 < 12; j4++) {
    float2 a01 = *(const float2*)&br2[j4 * 4];
    float2 a23 = *(const float2*)&br2[j4 * 4 + 2];
    #pragma unroll
    for (int k = 0; k < 64; k++) {
      float2 h2 = make_float2(h1[k], h1[k]);
      a01 = f2fma(h2, *(const float2*)&Wr2[k * 48 + j4 * 4],     a01);
      a23 = f2fma(h2, *(const float2*)&Wr2[k * 48 + j4 * 4 + 2], a23);
    }
    *(float4*)(recB + (j4 - 6) * 4) = make_float4(siluf(a01.x) * fc, siluf(a01.y) * fc,
                                                  siluf(a23.x) * fc, siluf(a23.y) * fc);
  }
  *(float4*)(recB + 24) = make_float4(x * invd, y * invd, z * invd, 0.0f);
}

// ---------------- k_atom: one wave per atom, contiguous sorted runs, 8-FMA CORE ----------------
__global__ __launch_bounds__(128) void k_atom(
    const float* __restrict__ ws,
    const float* __restrict__ Wa1, const float* __restrict__ ba1,
    const float* __restrict__ Wa2, const float* __restrict__ ba2,
    const float* __restrict__ Wa3, const float* __restrict__ ba3,
    float* __restrict__ out)
{
  __shared__ __align__(16) float sScr[2][1920];
  int tid = threadIdx.x;
  int lane = tid & 63, wv = tid >> 6;
  int a = blockIdx.x * 2 + wv;          // NATOMS = 5000*2 exact
  float* sStage = &sScr[wv][0];
  float* sG     = &sScr[wv][768];
  float* sFeat  = &sScr[wv][1632];
  float* sH     = &sScr[wv][1824];

  int4 o = ((const int4*)(ws + WS_OFFS))[a];

  const int c = lane;
  bool isc = (c < 35);
  int pa = 0, pb = 0, pcw = 0, lb = 0;
  if (isc) { pa = d_PWA[c]; pb = d_PWB[c]; pcw = d_PWC[c]; lb = d_LBLK[c]; }
  int rdir = lane - 35;
  bool isd = (rdir >= 0) && (rdir < 8);
  int rl = lane >> 4, fl = lane & 15;
  const float* gsrc = ws + (fl < 6 ? WS_SA : WS_SB);
  int foff = (fl < 6) ? fl : ((fl < 13) ? fl - 6 : 6);

  float2 g2[3][4];
  #pragma unroll
  for (int t2 = 0; t2 < 3; t2++)
    #pragma unroll
    for (int r = 0; r < 4; r++) g2[t2][r] = make_float2(0.f, 0.f);
  float g0[3] = {0.0f, 0.0f, 0.0f};

#define CORE(T) {                                                             \
    const float* rb = buf + j * 64;                                           \
    if (isc) {                                                                \
      float comp = psel(rb[48], pa) * psel(rb[49], pb) * psel(rb[50], pcw);   \
      float2 c2 = make_float2(comp, comp);                                    \
      const float2* r2 = (const float2*)(rb + 8 + 8 * lb);                    \
      g2[T][0] = f2fma(c2, r2[0], g2[T][0]);                                  \
      g2[T][1] = f2fma(c2, r2[1], g2[T][1]);                                  \
      g2[T][2] = f2fma(c2, r2[2], g2[T][2]);                                  \
      g2[T][3] = f2fma(c2, r2[3], g2[T][3]);                                  \
    } else if (isd) {                                                         \
      g0[T] += rb[rdir];                                                      \
    }                                                                         \
  }

#define LOADR(Q, DST) {                                                       \
    int sl_ = (Q) * 4 + rl; if (sl_ >= m) sl_ = m - 1;                        \
    DST = *(const float4*)(gsrc + (size_t)(cb + sl_) * 32 + foff * 4);        \
  }

#define RUN(T, LO, HI)                                                        \
  for (int cb = (LO); cb < (HI); cb += 64) {                                  \
    int m = (HI) - cb; if (m > 64) m = 64;                                    \
    int R = (m + 3) >> 2;                                                     \
    float4 v0, v1;                                                            \
    LOADR(0, v0)                                                              \
    if (R > 1) { LOADR(1, v1) } else v1 = v0;                                 \
    int bsel = 0;                                                             \
    for (int r = 0; r < R; r++) {                                             \
      float* buf = sStage + (bsel << 8);                                      \
      bsel = (bsel == 2) ? 0 : bsel + 1;                                      \
      *(float4*)(buf + rl * 64 + fl * 4) = v0;                                \
      v0 = v1;                                                                \
      if (r + 2 < R) LOADR(r + 2, v1)                                         \
      int g = r * 4, gm = m - g; if (gm > 4) gm = 4;                          \
      for (int j = 0; j < gm; j++) CORE(T)                                    \
    }                                                                         \
  }

  RUN(0, o.x, o.y)
  RUN(1, o.y, o.z)
  RUN(2, o.z, o.w)
#undef RUN
#undef CORE
#undef LOADR

  if (isc) {
    #pragma unroll
    for (int t2 = 0; t2 < 3; t2++)
      #pragma unroll
      for (int r = 0; r < 8; r++) {
        float gval = (r & 1) ? g2[t2][r >> 1].y : g2[t2][r >> 1].x;
        sG[(t2 * 8 + r) * 36 + c] = gval;
      }
  } else if (isd) {
    #pragma unroll
    for (int t2 = 0; t2 < 3; t2++) sG[(t2 * 8 + rdir) * 36 + 35] = g0[t2];
  }

  int s = lane & 3;
  float se0 = ws[WS_SEMB + s], se1 = ws[WS_SEMB + 4 + s], se2 = ws[WS_SEMB + 8 + s];
  float fout[3];
  #pragma unroll
  for (int u = 0; u < 3; u++) {
    int f = lane + 64 * u;
    int blk = f >> 5, rr = (f >> 2) & 7;
    float acc;
    if (blk == 0) {
      acc = se0 * sG[(0 + rr) * 36 + 35] + se1 * sG[(8 + rr) * 36 + 35] + se2 * sG[(16 + rr) * 36 + 35];
    } else {
      int c0 = d_L6[blk - 1], c1 = d_L6[blk];
      acc = 0.0f;
      for (int cc = c0; cc < c1; cc++) {
        float A = se0 * sG[(0 + rr) * 36 + cc] + se1 * sG[(8 + rr) * 36 + cc] + se2 * sG[(16 + rr) * 36 + cc];
        acc += d_NM[cc] * A * A;
      }
    }
    fout[u] = acc;
  }
  #pragma unroll
  for (int u = 0; u < 3; u++) sFeat[lane + 64 * u] = fout[u];

  {
    float a0 = 0.f, a1 = 0.f, a2 = 0.f, a3 = 0.f;
    for (int k4 = 0; k4 < 48; k4++) {
      float4 f4 = *(const float4*)(sFeat + k4 * 4);
      const float* w = Wa1 + (k4 * 4) * 64 + lane;
      a0 += f4.x * w[0];
      a1 += f4.y * w[64];
      a2 += f4.z * w[128];
      a3 += f4.w * w[192];
    }
    sH[lane] = siluf(a0 + a1 + a2 + a3 + ba1[lane]);
  }

  {
    float a0 = 0.f, a1 = 0.f, a2 = 0.f, a3 = 0.f;
    for (int k4 = 0; k4 < 16; k4++) {
      float4 h4 = *(const float4*)(sH + k4 * 4);
      const float* w = Wa2 + (k4 * 4) * 64 + lane;
      a0 += h4.x * w[0];
      a1 += h4.y * w[64];
      a2 += h4.z * w[128];
      a3 += h4.w * w[192];
    }
    float h2 = siluf(a0 + a1 + a2 + a3 + ba2[lane]);
    float pr = h2 * Wa3[lane];
    #pragma unroll
    for (int off = 32; off > 0; off >>= 1) pr += __shfl_down(pr, off, 64);
    if (lane == 0) out[a] = pr + ba3[0];
  }
}

extern "C" void kernel_launch(void* const* d_in, const int* in_sizes, int n_in,
                              void* d_out, int out_size, void* d_ws, size_t ws_size,
                              hipStream_t stream)
{
  const float* rij         = (const float*)d_in[0];
  const int*   species     = (const int*)  d_in[1];
  const int*   first_atom  = (const int*)  d_in[2];
  const int*   second_atom = (const int*)  d_in[3];
  const float* Wr1 = (const float*)d_in[4];
  const float* br1 = (const float*)d_in[5];
  const float* Wr2 = (const float*)d_in[6];
  const float* br2 = (const float*)d_in[7];
  const float* Ws1 = (const float*)d_in[8];
  const float* bs1 = (const float*)d_in[9];
  const float* Ws2 = (const float*)d_in[10];
  const float* bs2 = (const float*)d_in[11];
  const float* Wa1 = (const float*)d_in[12];
  const float* ba1 = (const float*)d_in[13];
  const float* Wa2 = (const float*)d_in[14];
  const float* ba2 = (const float*)d_in[15];
  const float* Wa3 = (const float*)d_in[16];
  const float* ba3 = (const float*)d_in[17];
  float* ws  = (float*)d_ws;
  float* out = (float*)d_out;

  k_init<<<(NBINS + 255) / 256, 256, 0, stream>>>(Ws1, bs1, Ws2, bs2, ws);
  k_hist<<<(NEDGES + 255) / 256, 256, 0, stream>>>(first_atom, second_atom, species, ws);
  k_alloc<<<(NATOMS + 255) / 256, 256, 0, stream>>>(ws);
  k_edge<<<NEDGES / 256, 256, 0, stream>>>(rij, species, first_atom, second_atom,
                                           Wr1, br1, Wr2, br2, ws);
  k_atom<<<NATOMS / 2, 128, 0, stream>>>(ws, Wa1, ba1, Wa2, ba2, Wa3, ba3, out);
}

// Round 2
// 205.776 us; speedup vs baseline: 1.0785x; 1.0785x over previous
//
#include <hip/hip_runtime.h>
#include <math.h>

#define NATOMS 10000
#define NEDGES 320000
#define NBINS  (NATOMS * 4)   // bin = atom*4 + species; bin a*4+3 always empty
#define RC_F 5.0f
#define PI_F 3.14159265358979323846f

// radial table: T[k][0..47] = (R * fc)(d_k), d_k = k * RC/(NK-1)
#define NK   4096
#define TROW 48
#define HINV_F ((float)(NK - 1) / RC_F)   // 819.0

// ---- workspace layout (in floats) ----
#define WS_SEMB   0         // 12 floats
#define WS_GTOT   12        // 1 int global allocation cursor
#define WS_CNT    16        // NBINS ints
#define WS_OFFS   40016     // NBINS ints (int4/atom: run starts t=0,1,2 + end)
#define WS_CURSOR 80016     // NBINS ints
#define WS_EIDX   120016    // NEDGES ints: edge id, (atom,species)-sorted
#define WS_TAB    440096    // NK*TROW floats (786 KB) radial table

// multinomial term tables (global component index 0..34)
__device__ __constant__ int   d_PWA[35] = {0, 0,0,1, 0,0,0,1,1,2, 0,0,0,0,1,1,1,2,2,3, 0,0,0,0,0,1,1,1,1,2,2,2,3,3,4};
__device__ __constant__ int   d_PWB[35] = {0, 0,1,0, 0,1,2,0,1,0, 0,1,2,3,0,1,2,0,1,0, 0,1,2,3,4,0,1,2,3,0,1,2,0,1,0};
__device__ __constant__ int   d_PWC[35] = {0, 1,0,0, 2,1,0,1,0,0, 3,2,1,0,2,1,0,1,0,0, 4,3,2,1,0,3,2,1,0,2,1,0,1,0,0};
__device__ __constant__ float d_NM[35]  = {1.f, 1.f,1.f,1.f, 1.f,2.f,1.f,2.f,2.f,1.f,
                                           1.f,3.f,3.f,1.f,3.f,6.f,3.f,3.f,3.f,1.f,
                                           1.f,4.f,6.f,4.f,1.f,4.f,12.f,12.f,4.f,6.f,12.f,6.f,4.f,4.f,1.f};
__device__ __constant__ int   d_LBLK[35]= {0, 1,1,1, 2,2,2,2,2,2, 3,3,3,3,3,3,3,3,3,3, 4,4,4,4,4,4,4,4,4,4,4,4,4,4,4};
__device__ __constant__ int   d_L6[6]   = {0,1,4,10,20,35};

__device__ __forceinline__ float siluf(float x) { return x / (1.0f + __expf(-x)); }

__device__ __forceinline__ float2 f2fma(float2 a, float2 b, float2 c) {
  return make_float2(fmaf(a.x, b.x, c.x), fmaf(a.y, b.y, c.y));
}

__device__ __forceinline__ float psel(float x, int p) {
  float x2 = x * x;
  float r = 1.0f;
  r = (p == 1) ? x : r;
  r = (p == 2) ? x2 : r;
  r = (p == 3) ? x2 * x : r;
  r = (p == 4) ? x2 * x2 : r;
  return r;
}

// ---------------- k_init ----------------
__global__ void k_init(const float* __restrict__ Ws1, const float* __restrict__ bs1,
                       const float* __restrict__ Ws2, const float* __restrict__ bs2,
                       float* __restrict__ ws)
{
  int tid = blockIdx.x * blockDim.x + threadIdx.x;
  int* cnt = (int*)(ws + WS_CNT);
  if (tid < NBINS) cnt[tid] = 0;
  if (tid == 0) *(int*)(ws + WS_GTOT) = 0;
  if (tid < 12) {
    int t = tid >> 2, s = tid & 3;
    float acc = bs2[s];
    for (int j = 0; j < 16; j++) acc += tanhf(Ws1[t * 16 + j] + bs1[j]) * Ws2[j * 4 + s];
    ws[WS_SEMB + tid] = acc;
  }
}

// ---------------- k_table: radial MLP tabulated over d in [0, RC] ----------------
// thread = (slice sl=0..11, local knot); each computes h1 then its 4 outputs.
__global__ __launch_bounds__(192) void k_table(
    const float* __restrict__ Wr1, const float* __restrict__ br1,
    const float* __restrict__ Wr2, const float* __restrict__ br2,
    float* __restrict__ ws)
{
  int sl = threadIdx.x;                      // 0..11
  int k  = blockIdx.x * 16 + threadIdx.y;    // knot 0..NK-1
  float dk = (float)k * (RC_F / (float)(NK - 1));
  float d = fmaxf(dk, 1e-6f);                // matches sqrt(r^2+1e-12) >= 1e-6
  float invd = 1.0f / d;

  float theta = (PI_F / RC_F) * d;
  float s1 = sinf(theta), c1 = cosf(theta);
  float fc = (d < RC_F) ? 0.5f * (c1 + 1.0f) : 0.0f;
  float bes[8];
  {
    float sq = sqrtf(2.0f / RC_F) * invd;
    float twoc = 2.0f * c1;
    float sp = 0.0f, sc = s1;
    #pragma unroll
    for (int q = 0; q < 8; q++) {
      bes[q] = sq * sc;
      float sn = twoc * sc - sp;
      sp = sc; sc = sn;
    }
  }

  float h1[64];
  #pragma unroll
  for (int j4 = 0; j4 < 16; j4++) {
    float2 a01 = *(const float2*)&br1[j4 * 4];
    float2 a23 = *(const float2*)&br1[j4 * 4 + 2];
    #pragma unroll
    for (int q = 0; q < 8; q++) {
      float2 b2 = make_float2(bes[q], bes[q]);
      a01 = f2fma(b2, *(const float2*)&Wr1[q * 64 + j4 * 4],     a01);
      a23 = f2fma(b2, *(const float2*)&Wr1[q * 64 + j4 * 4 + 2], a23);
    }
    h1[j4 * 4 + 0] = siluf(a01.x);
    h1[j4 * 4 + 1] = siluf(a01.y);
    h1[j4 * 4 + 2] = siluf(a23.x);
    h1[j4 * 4 + 3] = siluf(a23.y);
  }

  int j0 = sl * 4;
  float2 a01 = *(const float2*)&br2[j0];
  float2 a23 = *(const float2*)&br2[j0 + 2];
  for (int q = 0; q < 64; q++) {
    float2 h2 = make_float2(h1[q], h1[q]);
    a01 = f2fma(h2, *(const float2*)&Wr2[q * 48 + j0],     a01);
    a23 = f2fma(h2, *(const float2*)&Wr2[q * 48 + j0 + 2], a23);
  }
  *(float4*)(ws + WS_TAB + (size_t)k * TROW + j0) =
      make_float4(siluf(a01.x) * fc, siluf(a01.y) * fc,
                  siluf(a23.x) * fc, siluf(a23.y) * fc);
}

// ---------------- k_hist: (atom,species)-bin counts ----------------
__global__ void k_hist(const int* __restrict__ first_atom, const int* __restrict__ second_atom,
                       const int* __restrict__ species, float* __restrict__ ws)
{
  int e = blockIdx.x * blockDim.x + threadIdx.x;
  if (e < NEDGES) {
    int* cnt = (int*)(ws + WS_CNT);
    int bin = first_atom[e] * 4 + species[second_atom[e]];
    atomicAdd(&cnt[bin], 1);
  }
}

// ---------------- k_alloc: decentralized run allocation, int4 per atom ----------------
__global__ __launch_bounds__(256) void k_alloc(float* __restrict__ ws)
{
  const int4* cnt4 = (const int4*)(ws + WS_CNT);
  int4* offs4   = (int4*)(ws + WS_OFFS);
  int4* cursor4 = (int4*)(ws + WS_CURSOR);
  int* gtot = (int*)(ws + WS_GTOT);
  __shared__ int wsum[4];
  __shared__ int sbase;
  int tid = threadIdx.x;
  int lane = tid & 63, wv = tid >> 6;
  int a = blockIdx.x * 256 + tid;
  bool live = (a < NATOMS);
  int4 c = live ? cnt4[a] : make_int4(0, 0, 0, 0);
  int s = c.x + c.y + c.z + c.w;
  int inc = s;
  #pragma unroll
  for (int d = 1; d < 64; d <<= 1) {
    int v = __shfl_up(inc, d, 64);
    if (lane >= d) inc += v;
  }
  if (lane == 63) wsum[wv] = inc;
  __syncthreads();
  if (tid == 0) sbase = atomicAdd(gtot, wsum[0] + wsum[1] + wsum[2] + wsum[3]);
  __syncthreads();
  int woff = sbase;
  for (int w = 0; w < wv; w++) woff += wsum[w];
  int o0 = woff + inc - s;
  if (live) {
    int4 o;
    o.x = o0;
    o.y = o.x + c.x;
    o.z = o.y + c.y;
    o.w = o.z + c.z;
    offs4[a] = o;
    cursor4[a] = o;
  }
}

// ---------------- k_scatter: build sorted edge-index permutation ----------------
__global__ __launch_bounds__(256) void k_scatter(
    const int* __restrict__ first_atom, const int* __restrict__ second_atom,
    const int* __restrict__ species, float* __restrict__ ws)
{
  int e = blockIdx.x * 256 + threadIdx.x;
  int* cursor = (int*)(ws + WS_CURSOR);
  int* eidx   = (int*)(ws + WS_EIDX);
  int a = first_atom[e];
  int t = species[second_atom[e]];
  int pos = atomicAdd(&cursor[a * 4 + t], 1);
  eidx[pos] = e;   // 1.25 MB region, L2-absorbed
}

// ---------------- k_atom: one wave per atom; on-the-fly table-interp records ----------------
__global__ __launch_bounds__(128) void k_atom(
    const float* __restrict__ ws, const float* __restrict__ rijg,
    const float* __restrict__ Wa1, const float* __restrict__ ba1,
    const float* __restrict__ Wa2, const float* __restrict__ ba2,
    const float* __restrict__ Wa3, const float* __restrict__ ba3,
    float* __restrict__ out)
{
  __shared__ __align__(16) float sScr[2][2784];
  int tid = threadIdx.x;
  int lane = tid & 63, wv = tid >> 6;
  int a = blockIdx.x * 2 + wv;          // NATOMS = 5000*2 exact
  float* sStage = &sScr[wv][0];         // 32 records x 52 floats
  float* sG     = &sScr[wv][1664];      // 24 x 36
  float* sFeat  = &sScr[wv][2528];      // 192
  float* sH     = &sScr[wv][2720];      // 64

  const int* eidx = (const int*)(ws + WS_EIDX);
  const float* tab = ws + WS_TAB;
  int4 o = ((const int4*)(ws + WS_OFFS))[a];

  const int c = lane;
  bool isc = (c < 35);
  int pa = 0, pb = 0, pcw = 0, lb = 0;
  if (isc) { pa = d_PWA[c]; pb = d_PWB[c]; pcw = d_PWC[c]; lb = d_LBLK[c]; }
  int rdir = lane - 35;
  bool isd = (rdir >= 0) && (rdir < 8);
  int rl = lane >> 4, fl = lane & 15;

  float2 g2[3][4];
  #pragma unroll
  for (int t2 = 0; t2 < 3; t2++)
    #pragma unroll
    for (int r = 0; r < 4; r++) g2[t2][r] = make_float2(0.f, 0.f);
  float g0[3] = {0.0f, 0.0f, 0.0f};

#define CORE(T) {                                                             \
    const float* rb = sStage + j * 52;                                        \
    if (isc) {                                                                \
      float comp = psel(rb[48], pa) * psel(rb[49], pb) * psel(rb[50], pcw);   \
      float2 c2v = make_float2(comp, comp);                                   \
      const float2* r2 = (const float2*)(rb + 8 + 8 * lb);                    \
      g2[T][0] = f2fma(c2v, r2[0], g2[T][0]);                                 \
      g2[T][1] = f2fma(c2v, r2[1], g2[T][1]);                                 \
      g2[T][2] = f2fma(c2v, r2[2], g2[T][2]);                                 \
      g2[T][3] = f2fma(c2v, r2[3], g2[T][3]);                                 \
    } else if (isd) {                                                         \
      g0[T] += rb[rdir];                                                      \
    }                                                                         \
  }

#define RUN(T, LO, HI)                                                        \
  for (int cb = (LO); cb < (HI); cb += 32) {                                  \
    int m = (HI) - cb; if (m > 32) m = 32;                                    \
    int pp = cb + lane;                                                       \
    int e = eidx[(lane < m) ? pp : cb];                                       \
    float x = rijg[e * 3 + 0], y = rijg[e * 3 + 1], z = rijg[e * 3 + 2];      \
    float dd = sqrtf(x * x + y * y + z * z + 1e-12f);                         \
    float invd = 1.0f / dd;                                                   \
    float rx = x * invd, ry = y * invd, rz = z * invd;                        \
    float fi = dd * HINV_F;                                                   \
    int ii = (int)fi;                                                         \
    ii = (ii < 1) ? 1 : ((ii > NK - 3) ? NK - 3 : ii);                        \
    float w = fi - (float)ii;                                                 \
    float wm = w - 1.0f, wp = w + 1.0f, w2c = w - 2.0f;                       \
    float l0 = -w * wm * w2c * (1.0f / 6.0f);                                 \
    float l1 = wp * wm * w2c * 0.5f;                                          \
    float l2 = -wp * w * w2c * 0.5f;                                          \
    float l3 = wp * w * wm * (1.0f / 6.0f);                                   \
    int rowb = (ii - 1) * TROW;                                               \
    int R = (m + 3) >> 2;                                                     \
    for (int r = 0; r < R; r++) {                                             \
      int sl = r * 4 + rl;                                                    \
      float b0 = __shfl(l0, sl, 64), b1 = __shfl(l1, sl, 64);                 \
      float b2 = __shfl(l2, sl, 64), b3 = __shfl(l3, sl, 64);                 \
      int   rbI = __shfl(rowb, sl, 64);                                       \
      float sx = __shfl(rx, sl, 64), sy = __shfl(ry, sl, 64);                 \
      float sz = __shfl(rz, sl, 64);                                          \
      if (fl < 12) {                                                          \
        const float* tp = tab + rbI + fl * 4;                                 \
        float4 t0 = *(const float4*)(tp);                                     \
        float4 t1 = *(const float4*)(tp + TROW);                              \
        float4 t2 = *(const float4*)(tp + 2 * TROW);                          \
        float4 t3 = *(const float4*)(tp + 3 * TROW);                          \
        float4 v;                                                             \
        v.x = fmaf(b3, t3.x, fmaf(b2, t2.x, fmaf(b1, t1.x, b0 * t0.x)));      \
        v.y = fmaf(b3, t3.y, fmaf(b2, t2.y, fmaf(b1, t1.y, b0 * t0.y)));      \
        v.z = fmaf(b3, t3.z, fmaf(b2, t2.z, fmaf(b1, t1.z, b0 * t0.z)));      \
        v.w = fmaf(b3, t3.w, fmaf(b2, t2.w, fmaf(b1, t1.w, b0 * t0.w)));      \
        *(float4*)(sStage + sl * 52 + fl * 4) = v;                            \
      } else if (fl == 12) {                                                  \
        *(float4*)(sStage + sl * 52 + 48) = make_float4(sx, sy, sz, 0.0f);    \
      }                                                                       \
    }                                                                         \
    for (int j = 0; j < m; j++) CORE(T)                                       \
  }

  RUN(0, o.x, o.y)
  RUN(1, o.y, o.z)
  RUN(2, o.z, o.w)
#undef RUN
#undef CORE

  if (isc) {
    #pragma unroll
    for (int t2 = 0; t2 < 3; t2++)
      #pragma unroll
      for (int r = 0; r < 8; r++) {
        float gval = (r & 1) ? g2[t2][r >> 1].y : g2[t2][r >> 1].x;
        sG[(t2 * 8 + r) * 36 + c] = gval;
      }
  } else if (isd) {
    #pragma unroll
    for (int t2 = 0; t2 < 3; t2++) sG[(t2 * 8 + rdir) * 36 + 35] = g0[t2];
  }

  int s = lane & 3;
  float se0 = ws[WS_SEMB + s], se1 = ws[WS_SEMB + 4 + s], se2 = ws[WS_SEMB + 8 + s];
  float fout[3];
  #pragma unroll
  for (int u = 0; u < 3; u++) {
    int f = lane + 64 * u;
    int blk = f >> 5, rr = (f >> 2) & 7;
    float acc;
    if (blk == 0) {
      acc = se0 * sG[(0 + rr) * 36 + 35] + se1 * sG[(8 + rr) * 36 + 35] + se2 * sG[(16 + rr) * 36 + 35];
    } else {
      int c0 = d_L6[blk - 1], c1 = d_L6[blk];
      acc = 0.0f;
      for (int cc = c0; cc < c1; cc++) {
        float A = se0 * sG[(0 + rr) * 36 + cc] + se1 * sG[(8 + rr) * 36 + cc] + se2 * sG[(16 + rr) * 36 + cc];
        acc += d_NM[cc] * A * A;
      }
    }
    fout[u] = acc;
  }
  #pragma unroll
  for (int u = 0; u < 3; u++) sFeat[lane + 64 * u] = fout[u];

  {
    float a0 = 0.f, a1 = 0.f, a2 = 0.f, a3 = 0.f;
    for (int k4 = 0; k4 < 48; k4++) {
      float4 f4 = *(const float4*)(sFeat + k4 * 4);
      const float* wp = Wa1 + (k4 * 4) * 64 + lane;
      a0 += f4.x * wp[0];
      a1 += f4.y * wp[64];
      a2 += f4.z * wp[128];
      a3 += f4.w * wp[192];
    }
    sH[lane] = siluf(a0 + a1 + a2 + a3 + ba1[lane]);
  }

  {
    float a0 = 0.f, a1 = 0.f, a2 = 0.f, a3 = 0.f;
    for (int k4 = 0; k4 < 16; k4++) {
      float4 h4 = *(const float4*)(sH + k4 * 4);
      const float* wp = Wa2 + (k4 * 4) * 64 + lane;
      a0 += h4.x * wp[0];
      a1 += h4.y * wp[64];
      a2 += h4.z * wp[128];
      a3 += h4.w * wp[192];
    }
    float h2 = siluf(a0 + a1 + a2 + a3 + ba2[lane]);
    float pr = h2 * Wa3[lane];
    #pragma unroll
    for (int off = 32; off > 0; off >>= 1) pr += __shfl_down(pr, off, 64);
    if (lane == 0) out[a] = pr + ba3[0];
  }
}

extern "C" void kernel_launch(void* const* d_in, const int* in_sizes, int n_in,
                              void* d_out, int out_size, void* d_ws, size_t ws_size,
                              hipStream_t stream)
{
  const float* rij         = (const float*)d_in[0];
  const int*   species     = (const int*)  d_in[1];
  const int*   first_atom  = (const int*)  d_in[2];
  const int*   second_atom = (const int*)  d_in[3];
  const float* Wr1 = (const float*)d_in[4];
  const float* br1 = (const float*)d_in[5];
  const float* Wr2 = (const float*)d_in[6];
  const float* br2 = (const float*)d_in[7];
  const float* Ws1 = (const float*)d_in[8];
  const float* bs1 = (const float*)d_in[9];
  const float* Ws2 = (const float*)d_in[10];
  const float* bs2 = (const float*)d_in[11];
  const float* Wa1 = (const float*)d_in[12];
  const float* ba1 = (const float*)d_in[13];
  const float* Wa2 = (const float*)d_in[14];
  const float* ba2 = (const float*)d_in[15];
  const float* Wa3 = (const float*)d_in[16];
  const float* ba3 = (const float*)d_in[17];
  float* ws  = (float*)d_ws;
  float* out = (float*)d_out;

  k_init<<<(NBINS + 255) / 256, 256, 0, stream>>>(Ws1, bs1, Ws2, bs2, ws);
  k_table<<<NK / 16, dim3(12, 16), 0, stream>>>(Wr1, br1, Wr2, br2, ws);
  k_hist<<<(NEDGES + 255) / 256, 256, 0, stream>>>(first_atom, second_atom, species, ws);
  k_alloc<<<(NATOMS + 255) / 256, 256, 0, stream>>>(ws);
  k_scatter<<<NEDGES / 256, 256, 0, stream>>>(first_atom, second_atom, species, ws);
  k_atom<<<NATOMS / 2, 128, 0, stream>>>(ws, rij, Wa1, ba1, Wa2, ba2, Wa3, ba3, out);
}

// Round 3
// 186.816 us; speedup vs baseline: 1.1880x; 1.1015x over previous
//
#include <hip/hip_runtime.h>
#include <math.h>

#define NATOMS 10000
#define NEDGES 320000
#define NBINS  (NATOMS * 4)   // bin = atom*4 + species; bin a*4+3 always empty
#define RC_F 5.0f
#define PI_F 3.14159265358979323846f

// radial table: T[k][0..47] = (R * fc)(d_k), d_k = k * RC/(NK-1), linear interp
#define NK   16384
#define TROW 48
#define HINV_F ((float)(NK - 1) / RC_F)   // 3276.6

// ---- workspace layout (in floats) ----
#define WS_SEMB   0         // 12 floats
#define WS_GTOT   12        // 1 int global allocation cursor
#define WS_CNT    16        // NBINS ints
#define WS_OFFS   40016     // NBINS ints (int4/atom: run starts t=0,1,2 + end)
#define WS_CURSOR 80016     // NBINS ints
#define WS_BIN    120016    // NEDGES ints: cached bin per edge
#define WS_SD     440096    // NEDGES float4: (rx,ry,rz,d), (atom,species)-sorted
#define WS_TAB    1720096   // NK*TROW floats (3 MB) radial table

// multinomial term tables (global component index 0..34)
__device__ __constant__ int   d_PWA[35] = {0, 0,0,1, 0,0,0,1,1,2, 0,0,0,0,1,1,1,2,2,3, 0,0,0,0,0,1,1,1,1,2,2,2,3,3,4};
__device__ __constant__ int   d_PWB[35] = {0, 0,1,0, 0,1,2,0,1,0, 0,1,2,3,0,1,2,0,1,0, 0,1,2,3,4,0,1,2,3,0,1,2,0,1,0};
__device__ __constant__ int   d_PWC[35] = {0, 1,0,0, 2,1,0,1,0,0, 3,2,1,0,2,1,0,1,0,0, 4,3,2,1,0,3,2,1,0,2,1,0,1,0,0};
__device__ __constant__ float d_NM[35]  = {1.f, 1.f,1.f,1.f, 1.f,2.f,1.f,2.f,2.f,1.f,
                                           1.f,3.f,3.f,1.f,3.f,6.f,3.f,3.f,3.f,1.f,
                                           1.f,4.f,6.f,4.f,1.f,4.f,12.f,12.f,4.f,6.f,12.f,6.f,4.f,4.f,1.f};
__device__ __constant__ int   d_LBLK[35]= {0, 1,1,1, 2,2,2,2,2,2, 3,3,3,3,3,3,3,3,3,3, 4,4,4,4,4,4,4,4,4,4,4,4,4,4,4};
__device__ __constant__ int   d_L6[6]   = {0,1,4,10,20,35};

__device__ __forceinline__ float siluf(float x) { return x / (1.0f + __expf(-x)); }

__device__ __forceinline__ float2 f2fma(float2 a, float2 b, float2 c) {
  return make_float2(fmaf(a.x, b.x, c.x), fmaf(a.y, b.y, c.y));
}

__device__ __forceinline__ float psel(float x, int p) {
  float x2 = x * x;
  float r = 1.0f;
  r = (p == 1) ? x : r;
  r = (p == 2) ? x2 : r;
  r = (p == 3) ? x2 * x : r;
  r = (p == 4) ? x2 * x2 : r;
  return r;
}

// ---------------- k_table: radial MLP tabulated over d in [0, RC]; fused init ----------------
// dim3(12,16): threadIdx.x = output slice 0..11, threadIdx.y = local knot.
__global__ __launch_bounds__(192) void k_table(
    const float* __restrict__ Wr1, const float* __restrict__ br1,
    const float* __restrict__ Wr2, const float* __restrict__ br2,
    const float* __restrict__ Ws1, const float* __restrict__ bs1,
    const float* __restrict__ Ws2, const float* __restrict__ bs2,
    float* __restrict__ ws)
{
  // ---- fused init (cnt zero, gtot, species embedding) ----
  int flat = blockIdx.x * 192 + threadIdx.y * 12 + threadIdx.x;
  int* cnt = (int*)(ws + WS_CNT);
  if (flat < NBINS) cnt[flat] = 0;
  if (flat == 0) *(int*)(ws + WS_GTOT) = 0;
  if (flat < 12) {
    int t = flat >> 2, s = flat & 3;
    float acc = bs2[s];
    for (int j = 0; j < 16; j++) acc += tanhf(Ws1[t * 16 + j] + bs1[j]) * Ws2[j * 4 + s];
    ws[WS_SEMB + flat] = acc;
  }

  // ---- table ----
  int sl = threadIdx.x;                      // 0..11
  int k  = blockIdx.x * 16 + threadIdx.y;    // knot 0..NK-1
  float dk = (float)k * (RC_F / (float)(NK - 1));
  float d = fmaxf(dk, 1e-6f);                // matches sqrt(r^2+1e-12) >= 1e-6
  float invd = 1.0f / d;

  float theta = (PI_F / RC_F) * d;
  float s1 = sinf(theta), c1 = cosf(theta);
  float fc = (d < RC_F) ? 0.5f * (c1 + 1.0f) : 0.0f;
  float bes[8];
  {
    float sq = sqrtf(2.0f / RC_F) * invd;
    float twoc = 2.0f * c1;
    float sp = 0.0f, sc = s1;
    #pragma unroll
    for (int q = 0; q < 8; q++) {
      bes[q] = sq * sc;
      float sn = twoc * sc - sp;
      sp = sc; sc = sn;
    }
  }

  float h1[64];
  #pragma unroll
  for (int j4 = 0; j4 < 16; j4++) {
    float2 a01 = *(const float2*)&br1[j4 * 4];
    float2 a23 = *(const float2*)&br1[j4 * 4 + 2];
    #pragma unroll
    for (int q = 0; q < 8; q++) {
      float2 b2 = make_float2(bes[q], bes[q]);
      a01 = f2fma(b2, *(const float2*)&Wr1[q * 64 + j4 * 4],     a01);
      a23 = f2fma(b2, *(const float2*)&Wr1[q * 64 + j4 * 4 + 2], a23);
    }
    h1[j4 * 4 + 0] = siluf(a01.x);
    h1[j4 * 4 + 1] = siluf(a01.y);
    h1[j4 * 4 + 2] = siluf(a23.x);
    h1[j4 * 4 + 3] = siluf(a23.y);
  }

  int j0 = sl * 4;
  float2 a01 = *(const float2*)&br2[j0];
  float2 a23 = *(const float2*)&br2[j0 + 2];
  for (int q = 0; q < 64; q++) {
    float2 h2 = make_float2(h1[q], h1[q]);
    a01 = f2fma(h2, *(const float2*)&Wr2[q * 48 + j0],     a01);
    a23 = f2fma(h2, *(const float2*)&Wr2[q * 48 + j0 + 2], a23);
  }
  *(float4*)(ws + WS_TAB + (size_t)k * TROW + j0) =
      make_float4(siluf(a01.x) * fc, siluf(a01.y) * fc,
                  siluf(a23.x) * fc, siluf(a23.y) * fc);
}

// ---------------- k_hist: (atom,species)-bin counts; caches bin[e] ----------------
__global__ __launch_bounds__(256) void k_hist(
    const int* __restrict__ first_atom, const int* __restrict__ second_atom,
    const int* __restrict__ species, float* __restrict__ ws)
{
  int e = blockIdx.x * 256 + threadIdx.x;   // grid exact: NEDGES = 1250*256
  int* cnt  = (int*)(ws + WS_CNT);
  int* binA = (int*)(ws + WS_BIN);
  int bin = first_atom[e] * 4 + species[second_atom[e]];
  atomicAdd(&cnt[bin], 1);
  binA[e] = bin;
}

// ---------------- k_alloc: decentralized run allocation, int4 per atom ----------------
__global__ __launch_bounds__(256) void k_alloc(float* __restrict__ ws)
{
  const int4* cnt4 = (const int4*)(ws + WS_CNT);
  int4* offs4   = (int4*)(ws + WS_OFFS);
  int4* cursor4 = (int4*)(ws + WS_CURSOR);
  int* gtot = (int*)(ws + WS_GTOT);
  __shared__ int wsum[4];
  __shared__ int sbase;
  int tid = threadIdx.x;
  int lane = tid & 63, wv = tid >> 6;
  int a = blockIdx.x * 256 + tid;
  bool live = (a < NATOMS);
  int4 c = live ? cnt4[a] : make_int4(0, 0, 0, 0);
  int s = c.x + c.y + c.z + c.w;
  int inc = s;
  #pragma unroll
  for (int d = 1; d < 64; d <<= 1) {
    int v = __shfl_up(inc, d, 64);
    if (lane >= d) inc += v;
  }
  if (lane == 63) wsum[wv] = inc;
  __syncthreads();
  if (tid == 0) sbase = atomicAdd(gtot, wsum[0] + wsum[1] + wsum[2] + wsum[3]);
  __syncthreads();
  int woff = sbase;
  for (int w = 0; w < wv; w++) woff += wsum[w];
  int o0 = woff + inc - s;
  if (live) {
    int4 o;
    o.x = o0;
    o.y = o.x + c.x;
    o.z = o.y + c.y;
    o.w = o.z + c.z;
    offs4[a] = o;
    cursor4[a] = o;
  }
}

// ---------------- k_scatter: write (rhat,d) float4 at sorted position ----------------
__global__ __launch_bounds__(256) void k_scatter(
    const float* __restrict__ rij, float* __restrict__ ws)
{
  int e = blockIdx.x * 256 + threadIdx.x;   // grid exact
  int* cursor = (int*)(ws + WS_CURSOR);
  const int* binA = (const int*)(ws + WS_BIN);
  int bin = binA[e];
  int pos = atomicAdd(&cursor[bin], 1);
  float x = rij[e * 3 + 0], y = rij[e * 3 + 1], z = rij[e * 3 + 2];
  float d = sqrtf(x * x + y * y + z * z + 1e-12f);
  float invd = 1.0f / d;
  ((float4*)(ws + WS_SD))[pos] = make_float4(x * invd, y * invd, z * invd, d);
}

// ---------------- k_atom: one wave per atom; streaming sorted runs + table interp ----------------
// LDS per wave = 1120 floats: sStage (16x52, lifetime RUN) overlaid with
// sG/sFeat/sH (lifetime post-RUN). 8960 B/block -> occupancy cap = 32 waves/CU.
__global__ __launch_bounds__(128) void k_atom(
    const float* __restrict__ ws,
    const float* __restrict__ Wa1, const float* __restrict__ ba1,
    const float* __restrict__ Wa2, const float* __restrict__ ba2,
    const float* __restrict__ Wa3, const float* __restrict__ ba3,
    float* __restrict__ out)
{
  __shared__ __align__(16) float sScr[2][1120];
  int tid = threadIdx.x;
  int lane = tid & 63, wv = tid >> 6;
  int a = blockIdx.x * 2 + wv;          // NATOMS = 5000*2 exact
  float* sStage = &sScr[wv][0];         // 16 records x 52 floats (during RUN)
  float* sG     = &sScr[wv][0];         // 24 x 36 (after RUN; overlays sStage)
  float* sFeat  = &sScr[wv][864];       // 192
  float* sH     = &sScr[wv][1056];      // 64

  const float4* sd4 = (const float4*)(ws + WS_SD);
  const float* tab = ws + WS_TAB;
  int4 o = ((const int4*)(ws + WS_OFFS))[a];

  const int c = lane;
  bool isc = (c < 35);
  int pa = 0, pb = 0, pcw = 0, lb = 0;
  if (isc) { pa = d_PWA[c]; pb = d_PWB[c]; pcw = d_PWC[c]; lb = d_LBLK[c]; }
  int rdir = lane - 35;
  bool isd = (rdir >= 0) && (rdir < 8);
  int rl = lane >> 4, fl = lane & 15;

  float2 g2[3][4];
  #pragma unroll
  for (int t2 = 0; t2 < 3; t2++)
    #pragma unroll
    for (int r = 0; r < 4; r++) g2[t2][r] = make_float2(0.f, 0.f);
  float g0[3] = {0.0f, 0.0f, 0.0f};

#define CORE(T) {                                                             \
    const float* rb = sStage + j * 52;                                        \
    if (isc) {                                                                \
      float4 rh = *(const float4*)(rb + 48);                                  \
      float comp = psel(rh.x, pa) * psel(rh.y, pb) * psel(rh.z, pcw);         \
      float2 c2v = make_float2(comp, comp);                                   \
      const float2* r2 = (const float2*)(rb + 8 + 8 * lb);                    \
      g2[T][0] = f2fma(c2v, r2[0], g2[T][0]);                                 \
      g2[T][1] = f2fma(c2v, r2[1], g2[T][1]);                                 \
      g2[T][2] = f2fma(c2v, r2[2], g2[T][2]);                                 \
      g2[T][3] = f2fma(c2v, r2[3], g2[T][3]);                                 \
    } else if (isd) {                                                         \
      g0[T] += rb[rdir];                                                      \
    }                                                                         \
  }

#define RUN(T, LO, HI)                                                        \
  for (int cb = (LO); cb < (HI); cb += 16) {                                  \
    int m = (HI) - cb; if (m > 16) m = 16;                                    \
    int pp = cb + lane;                                                       \
    float4 ed = sd4[(lane < m) ? pp : (HI - 1)];                              \
    float fi = ed.w * HINV_F;                                                 \
    int ii = (int)fi;                                                         \
    ii = (ii > NK - 2) ? (NK - 2) : ii;                                       \
    float w = fi - (float)ii;                                                 \
    int rowb = ii * TROW;                                                     \
    int R = (m + 3) >> 2;                                                     \
    for (int r = 0; r < R; r++) {                                             \
      int sl = r * 4 + rl;                                                    \
      float w_s = __shfl(w, sl, 64);                                          \
      int   rb_ = __shfl(rowb, sl, 64);                                       \
      float sx = __shfl(ed.x, sl, 64), sy = __shfl(ed.y, sl, 64);             \
      float sz = __shfl(ed.z, sl, 64);                                        \
      if (fl < 12) {                                                          \
        const float* tp = tab + rb_ + fl * 4;                                 \
        float4 t0 = *(const float4*)(tp);                                     \
        float4 t1 = *(const float4*)(tp + TROW);                              \
        float4 v;                                                             \
        v.x = fmaf(w_s, t1.x - t0.x, t0.x);                                   \
        v.y = fmaf(w_s, t1.y - t0.y, t0.y);                                   \
        v.z = fmaf(w_s, t1.z - t0.z, t0.z);                                   \
        v.w = fmaf(w_s, t1.w - t0.w, t0.w);                                   \
        *(float4*)(sStage + sl * 52 + fl * 4) = v;                            \
      } else if (fl == 12) {                                                  \
        *(float4*)(sStage + sl * 52 + 48) = make_float4(sx, sy, sz, 0.0f);    \
      }                                                                       \
    }                                                                         \
    for (int j = 0; j < m; j++) CORE(T)                                       \
  }

  RUN(0, o.x, o.y)
  RUN(1, o.y, o.z)
  RUN(2, o.z, o.w)
#undef RUN
#undef CORE

  if (isc) {
    #pragma unroll
    for (int t2 = 0; t2 < 3; t2++)
      #pragma unroll
      for (int r = 0; r < 8; r++) {
        float gval = (r & 1) ? g2[t2][r >> 1].y : g2[t2][r >> 1].x;
        sG[(t2 * 8 + r) * 36 + c] = gval;
      }
  } else if (isd) {
    #pragma unroll
    for (int t2 = 0; t2 < 3; t2++) sG[(t2 * 8 + rdir) * 36 + 35] = g0[t2];
  }

  int s = lane & 3;
  float se0 = ws[WS_SEMB + s], se1 = ws[WS_SEMB + 4 + s], se2 = ws[WS_SEMB + 8 + s];
  float fout[3];
  #pragma unroll
  for (int u = 0; u < 3; u++) {
    int f = lane + 64 * u;
    int blk = f >> 5, rr = (f >> 2) & 7;
    float acc;
    if (blk == 0) {
      acc = se0 * sG[(0 + rr) * 36 + 35] + se1 * sG[(8 + rr) * 36 + 35] + se2 * sG[(16 + rr) * 36 + 35];
    } else {
      int c0 = d_L6[blk - 1], c1 = d_L6[blk];
      acc = 0.0f;
      for (int cc = c0; cc < c1; cc++) {
        float A = se0 * sG[(0 + rr) * 36 + cc] + se1 * sG[(8 + rr) * 36 + cc] + se2 * sG[(16 + rr) * 36 + cc];
        acc += d_NM[cc] * A * A;
      }
    }
    fout[u] = acc;
  }
  #pragma unroll
  for (int u = 0; u < 3; u++) sFeat[lane + 64 * u] = fout[u];

  {
    float a0 = 0.f, a1 = 0.f, a2 = 0.f, a3 = 0.f;
    for (int k4 = 0; k4 < 48; k4++) {
      float4 f4 = *(const float4*)(sFeat + k4 * 4);
      const float* wp = Wa1 + (k4 * 4) * 64 + lane;
      a0 += f4.x * wp[0];
      a1 += f4.y * wp[64];
      a2 += f4.z * wp[128];
      a3 += f4.w * wp[192];
    }
    sH[lane] = siluf(a0 + a1 + a2 + a3 + ba1[lane]);
  }

  {
    float a0 = 0.f, a1 = 0.f, a2 = 0.f, a3 = 0.f;
    for (int k4 = 0; k4 < 16; k4++) {
      float4 h4 = *(const float4*)(sH + k4 * 4);
      const float* wp = Wa2 + (k4 * 4) * 64 + lane;
      a0 += h4.x * wp[0];
      a1 += h4.y * wp[64];
      a2 += h4.z * wp[128];
      a3 += h4.w * wp[192];
    }
    float h2 = siluf(a0 + a1 + a2 + a3 + ba2[lane]);
    float pr = h2 * Wa3[lane];
    #pragma unroll
    for (int off = 32; off > 0; off >>= 1) pr += __shfl_down(pr, off, 64);
    if (lane == 0) out[a] = pr + ba3[0];
  }
}

extern "C" void kernel_launch(void* const* d_in, const int* in_sizes, int n_in,
                              void* d_out, int out_size, void* d_ws, size_t ws_size,
                              hipStream_t stream)
{
  const float* rij         = (const float*)d_in[0];
  const int*   species     = (const int*)  d_in[1];
  const int*   first_atom  = (const int*)  d_in[2];
  const int*   second_atom = (const int*)  d_in[3];
  const float* Wr1 = (const float*)d_in[4];
  const float* br1 = (const float*)d_in[5];
  const float* Wr2 = (const float*)d_in[6];
  const float* br2 = (const float*)d_in[7];
  const float* Ws1 = (const float*)d_in[8];
  const float* bs1 = (const float*)d_in[9];
  const float* Ws2 = (const float*)d_in[10];
  const float* bs2 = (const float*)d_in[11];
  const float* Wa1 = (const float*)d_in[12];
  const float* ba1 = (const float*)d_in[13];
  const float* Wa2 = (const float*)d_in[14];
  const float* ba2 = (const float*)d_in[15];
  const float* Wa3 = (const float*)d_in[16];
  const float* ba3 = (const float*)d_in[17];
  float* ws  = (float*)d_ws;
  float* out = (float*)d_out;

  k_table<<<NK / 16, dim3(12, 16), 0, stream>>>(Wr1, br1, Wr2, br2, Ws1, bs1, Ws2, bs2, ws);
  k_hist<<<NEDGES / 256, 256, 0, stream>>>(first_atom, second_atom, species, ws);
  k_alloc<<<(NATOMS + 255) / 256, 256, 0, stream>>>(ws);
  k_scatter<<<NEDGES / 256, 256, 0, stream>>>(rij, ws);
  k_atom<<<NATOMS / 2, 128, 0, stream>>>(ws, Wa1, ba1, Wa2, ba2, Wa3, ba3, out);
}

// Round 7
// 172.633 us; speedup vs baseline: 1.2856x; 1.0822x over previous
//
#include <hip/hip_runtime.h>
#include <math.h>

#define NATOMS 10000
#define NEDGES 320000
#define CAP    64             // fixed record capacity per (atom,species) bin
#define RC_F 5.0f
#define PI_F 3.14159265358979323846f

// radial table: T[k][0..47] = (R * fc)(d_k), d_k = k * RC/(NK-1), linear interp
#define NK   16384
#define TROW 48
#define HINV_F ((float)(NK - 1) / RC_F)

// ---- workspace layout (in floats) ----
#define WS_SEMB   0         // 12 floats
#define WS_CNT    16        // NATOMS int4 (species counts 0..2, .w unused)
#define WS_SD     440096    // NATOMS*3*CAP float4 records (30.7 MB), fixed-cap bins
#define WS_TAB    8200096   // NK*TROW floats (3 MB) radial table

// multinomial term tables (global component index 0..34)
__device__ __constant__ int   d_PWA[35] = {0, 0,0,1, 0,0,0,1,1,2, 0,0,0,0,1,1,1,2,2,3, 0,0,0,0,0,1,1,1,1,2,2,2,3,3,4};
__device__ __constant__ int   d_PWB[35] = {0, 0,1,0, 0,1,2,0,1,0, 0,1,2,3,0,1,2,0,1,0, 0,1,2,3,4,0,1,2,3,0,1,2,0,1,0};
__device__ __constant__ int   d_PWC[35] = {0, 1,0,0, 2,1,0,1,0,0, 3,2,1,0,2,1,0,1,0,0, 4,3,2,1,0,3,2,1,0,2,1,0,1,0,0};
__device__ __constant__ float d_NM[35]  = {1.f, 1.f,1.f,1.f, 1.f,2.f,1.f,2.f,2.f,1.f,
                                           1.f,3.f,3.f,1.f,3.f,6.f,3.f,3.f,3.f,1.f,
                                           1.f,4.f,6.f,4.f,1.f,4.f,12.f,12.f,4.f,6.f,12.f,6.f,4.f,4.f,1.f};
__device__ __constant__ int   d_LBLK[35]= {0, 1,1,1, 2,2,2,2,2,2, 3,3,3,3,3,3,3,3,3,3, 4,4,4,4,4,4,4,4,4,4,4,4,4,4,4};
__device__ __constant__ int   d_L6[6]   = {0,1,4,10,20,35};

__device__ __forceinline__ float siluf(float x) { return x / (1.0f + __expf(-x)); }

__device__ __forceinline__ float2 f2fma(float2 a, float2 b, float2 c) {
  return make_float2(fmaf(a.x, b.x, c.x), fmaf(a.y, b.y, c.y));
}

__device__ __forceinline__ float psel(float x, int p) {
  float x2 = x * x;
  float r = 1.0f;
  r = (p == 1) ? x : r;
  r = (p == 2) ? x2 : r;
  r = (p == 3) ? x2 * x : r;
  r = (p == 4) ? x2 * x2 : r;
  return r;
}

// ---------------- k_pre: zero counters + species embedding + radial table ----------------
// grid 768 x 256 = 196608 threads = NK*12 table items exactly; zeroing rides along.
__global__ __launch_bounds__(256) void k_pre(
    const float* __restrict__ Wr1, const float* __restrict__ br1,
    const float* __restrict__ Wr2, const float* __restrict__ br2,
    const float* __restrict__ Ws1, const float* __restrict__ bs1,
    const float* __restrict__ Ws2, const float* __restrict__ bs2,
    float* __restrict__ ws)
{
  int gt = blockIdx.x * 256 + threadIdx.x;

  // zero cnt (int4 per atom)
  if (gt < NATOMS) ((int4*)(ws + WS_CNT))[gt] = make_int4(0, 0, 0, 0);
  // species embedding
  if (gt < 12) {
    int t = gt >> 2, s = gt & 3;
    float acc = bs2[s];
    for (int j = 0; j < 16; j++) acc += tanhf(Ws1[t * 16 + j] + bs1[j]) * Ws2[j * 4 + s];
    ws[WS_SEMB + gt] = acc;
  }

  // radial table: item = (knot k, slice sl)
  int sl = gt % 12;
  int k  = gt / 12;           // 0..NK-1 exactly
  float dk = (float)k * (RC_F / (float)(NK - 1));
  float d = fmaxf(dk, 1e-6f);
  float invd = 1.0f / d;
  float theta = (PI_F / RC_F) * d;
  float s1 = sinf(theta), c1 = cosf(theta);
  float fc = (d < RC_F) ? 0.5f * (c1 + 1.0f) : 0.0f;
  float bes[8];
  {
    float sq = sqrtf(2.0f / RC_F) * invd;
    float twoc = 2.0f * c1;
    float sp = 0.0f, sc = s1;
    #pragma unroll
    for (int q = 0; q < 8; q++) {
      bes[q] = sq * sc;
      float sn = twoc * sc - sp;
      sp = sc; sc = sn;
    }
  }
  float h1[64];
  #pragma unroll
  for (int j4 = 0; j4 < 16; j4++) {
    float2 a01 = *(const float2*)&br1[j4 * 4];
    float2 a23 = *(const float2*)&br1[j4 * 4 + 2];
    #pragma unroll
    for (int q = 0; q < 8; q++) {
      float2 b2 = make_float2(bes[q], bes[q]);
      a01 = f2fma(b2, *(const float2*)&Wr1[q * 64 + j4 * 4],     a01);
      a23 = f2fma(b2, *(const float2*)&Wr1[q * 64 + j4 * 4 + 2], a23);
    }
    h1[j4 * 4 + 0] = siluf(a01.x);
    h1[j4 * 4 + 1] = siluf(a01.y);
    h1[j4 * 4 + 2] = siluf(a23.x);
    h1[j4 * 4 + 3] = siluf(a23.y);
  }
  int j0 = sl * 4;
  float2 a01 = *(const float2*)&br2[j0];
  float2 a23 = *(const float2*)&br2[j0 + 2];
  for (int q = 0; q < 64; q++) {
    float2 h2 = make_float2(h1[q], h1[q]);
    a01 = f2fma(h2, *(const float2*)&Wr2[q * 48 + j0],     a01);
    a23 = f2fma(h2, *(const float2*)&Wr2[q * 48 + j0 + 2], a23);
  }
  *(float4*)(ws + WS_TAB + (size_t)k * TROW + j0) =
      make_float4(siluf(a01.x) * fc, siluf(a01.y) * fc,
                  siluf(a23.x) * fc, siluf(a23.y) * fc);
}

// ---------------- k_scatter: direct allocation into fixed-capacity bins ----------------
__global__ __launch_bounds__(256) void k_scatter(
    const float* __restrict__ rij,
    const int* __restrict__ first_atom, const int* __restrict__ second_atom,
    const int* __restrict__ species, float* __restrict__ ws)
{
  int e = blockIdx.x * 256 + threadIdx.x;   // grid exact: NEDGES = 1250*256
  int* cnt = (int*)(ws + WS_CNT);
  int a = first_atom[e];
  int t = species[second_atom[e]];
  int pos = atomicAdd(&cnt[a * 4 + t], 1);
  float x = rij[e * 3 + 0], y = rij[e * 3 + 1], z = rij[e * 3 + 2];
  float d = sqrtf(x * x + y * y + z * z + 1e-12f);
  float invd = 1.0f / d;
  if (pos < CAP)
    ((float4*)(ws + WS_SD))[(size_t)a * (3 * CAP) + t * CAP + pos] =
        make_float4(x * invd, y * invd, z * invd, d);
}

// ---------------- k_atom: one wave per atom (static schedule); fixed-cap species runs ----------------
__global__ __launch_bounds__(128) void k_atom(
    const float* __restrict__ ws,
    const float* __restrict__ Wa1, const float* __restrict__ ba1,
    const float* __restrict__ Wa2, const float* __restrict__ ba2,
    const float* __restrict__ Wa3, const float* __restrict__ ba3,
    float* __restrict__ out)
{
  __shared__ __align__(16) float sScr[2][1120];
  int tid = threadIdx.x;
  int lane = tid & 63, wv = tid >> 6;
  int a = blockIdx.x * 2 + wv;          // NATOMS = 5000*2 exact
  float* sStage = &sScr[wv][0];         // 16 records x 52 floats (during runs)
  float* sG     = &sScr[wv][0];         // 24 x 36 (after runs; overlays sStage)
  float* sFeat  = &sScr[wv][864];       // 192
  float* sH     = &sScr[wv][1056];      // 64

  const float4* sd4 = (const float4*)(ws + WS_SD);
  const float* tab = ws + WS_TAB;

  const int c = lane;
  bool isc = (c < 35);
  int pa = 0, pb = 0, pcw = 0, lb = 0;
  if (isc) { pa = d_PWA[c]; pb = d_PWB[c]; pcw = d_PWC[c]; lb = d_LBLK[c]; }
  int rdir = lane - 35;
  bool isd = (rdir >= 0) && (rdir < 8);
  int rl = lane >> 4, fl = lane & 15;
  int s = lane & 3;
  float se0 = ws[WS_SEMB + s], se1 = ws[WS_SEMB + 4 + s], se2 = ws[WS_SEMB + 8 + s];

  int4 cv = ((const int4*)(ws + WS_CNT))[a];
  int c0n = cv.x > CAP ? CAP : cv.x;
  int c1n = cv.y > CAP ? CAP : cv.y;
  int c2n = cv.z > CAP ? CAP : cv.z;

  float2 g2[3][4];
  #pragma unroll
  for (int t2 = 0; t2 < 3; t2++)
    #pragma unroll
    for (int r = 0; r < 4; r++) g2[t2][r] = make_float2(0.f, 0.f);
  float g0[3] = {0.0f, 0.0f, 0.0f};

#define CORE(T) {                                                             \
    const float* rb = sStage + j * 52;                                        \
    if (isc) {                                                                \
      float4 rh = *(const float4*)(rb + 48);                                  \
      float comp = psel(rh.x, pa) * psel(rh.y, pb) * psel(rh.z, pcw);         \
      float2 c2v = make_float2(comp, comp);                                   \
      const float2* r2 = (const float2*)(rb + 8 + 8 * lb);                    \
      g2[T][0] = f2fma(c2v, r2[0], g2[T][0]);                                 \
      g2[T][1] = f2fma(c2v, r2[1], g2[T][1]);                                 \
      g2[T][2] = f2fma(c2v, r2[2], g2[T][2]);                                 \
      g2[T][3] = f2fma(c2v, r2[3], g2[T][3]);                                 \
    } else if (isd) {                                                         \
      g0[T] += rb[rdir];                                                      \
    }                                                                         \
  }

#define RUNT(T, CT) {                                                         \
    const float4* rbase = sd4 + (size_t)a * (3 * CAP) + (T) * CAP;            \
    for (int cb = 0; cb < (CT); cb += 16) {                                   \
      int m = (CT) - cb; if (m > 16) m = 16;                                  \
      float4 ed = rbase[cb + ((lane < m) ? lane : (m - 1))];                  \
      float fi = ed.w * HINV_F;                                               \
      int ii = (int)fi;                                                       \
      ii = (ii > NK - 2) ? (NK - 2) : ii;                                     \
      float w = fi - (float)ii;                                               \
      int rowb = ii * TROW;                                                   \
      int R = (m + 3) >> 2;                                                   \
      for (int r = 0; r < R; r++) {                                           \
        int sl = r * 4 + rl;                                                  \
        float w_s = __shfl(w, sl, 64);                                        \
        int   rb_ = __shfl(rowb, sl, 64);                                     \
        float sx = __shfl(ed.x, sl, 64), sy = __shfl(ed.y, sl, 64);           \
        float sz = __shfl(ed.z, sl, 64);                                      \
        if (fl < 12) {                                                        \
          const float* tp = tab + rb_ + fl * 4;                               \
          float4 t0 = *(const float4*)(tp);                                   \
          float4 t1 = *(const float4*)(tp + TROW);                            \
          float4 v;                                                           \
          v.x = fmaf(w_s, t1.x - t0.x, t0.x);                                 \
          v.y = fmaf(w_s, t1.y - t0.y, t0.y);                                 \
          v.z = fmaf(w_s, t1.z - t0.z, t0.z);                                 \
          v.w = fmaf(w_s, t1.w - t0.w, t0.w);                                 \
          *(float4*)(sStage + sl * 52 + fl * 4) = v;                          \
        } else if (fl == 12) {                                                \
          *(float4*)(sStage + sl * 52 + 48) = make_float4(sx, sy, sz, 0.0f);  \
        }                                                                     \
      }                                                                       \
      for (int j = 0; j < m; j++) CORE(T)                                     \
    }                                                                         \
  }

  RUNT(0, c0n)
  RUNT(1, c1n)
  RUNT(2, c2n)
#undef RUNT
#undef CORE

  if (isc) {
    #pragma unroll
    for (int t2 = 0; t2 < 3; t2++)
      #pragma unroll
      for (int r = 0; r < 8; r++) {
        float gval = (r & 1) ? g2[t2][r >> 1].y : g2[t2][r >> 1].x;
        sG[(t2 * 8 + r) * 36 + c] = gval;
      }
  } else if (isd) {
    #pragma unroll
    for (int t2 = 0; t2 < 3; t2++) sG[(t2 * 8 + rdir) * 36 + 35] = g0[t2];
  }

  float fout[3];
  #pragma unroll
  for (int u = 0; u < 3; u++) {
    int f = lane + 64 * u;
    int blk = f >> 5, rr = (f >> 2) & 7;
    float acc;
    if (blk == 0) {
      acc = se0 * sG[(0 + rr) * 36 + 35] + se1 * sG[(8 + rr) * 36 + 35] + se2 * sG[(16 + rr) * 36 + 35];
    } else {
      int cc0 = d_L6[blk - 1], cc1 = d_L6[blk];
      acc = 0.0f;
      for (int cc = cc0; cc < cc1; cc++) {
        float A = se0 * sG[(0 + rr) * 36 + cc] + se1 * sG[(8 + rr) * 36 + cc] + se2 * sG[(16 + rr) * 36 + cc];
        acc += d_NM[cc] * A * A;
      }
    }
    fout[u] = acc;
  }
  #pragma unroll
  for (int u = 0; u < 3; u++) sFeat[lane + 64 * u] = fout[u];

  {
    float a0_ = 0.f, a1_ = 0.f, a2_ = 0.f, a3_ = 0.f;
    for (int k4 = 0; k4 < 48; k4++) {
      float4 f4 = *(const float4*)(sFeat + k4 * 4);
      const float* wp = Wa1 + (k4 * 4) * 64 + lane;
      a0_ += f4.x * wp[0];
      a1_ += f4.y * wp[64];
      a2_ += f4.z * wp[128];
      a3_ += f4.w * wp[192];
    }
    sH[lane] = siluf(a0_ + a1_ + a2_ + a3_ + ba1[lane]);
  }

  {
    float a0_ = 0.f, a1_ = 0.f, a2_ = 0.f, a3_ = 0.f;
    for (int k4 = 0; k4 < 16; k4++) {
      float4 h4 = *(const float4*)(sH + k4 * 4);
      const float* wp = Wa2 + (k4 * 4) * 64 + lane;
      a0_ += h4.x * wp[0];
      a1_ += h4.y * wp[64];
      a2_ += h4.z * wp[128];
      a3_ += h4.w * wp[192];
    }
    float h2 = siluf(a0_ + a1_ + a2_ + a3_ + ba2[lane]);
    float pr = h2 * Wa3[lane];
    #pragma unroll
    for (int off = 32; off > 0; off >>= 1) pr += __shfl_down(pr, off, 64);
    if (lane == 0) out[a] = pr + ba3[0];
  }
}

extern "C" void kernel_launch(void* const* d_in, const int* in_sizes, int n_in,
                              void* d_out, int out_size, void* d_ws, size_t ws_size,
                              hipStream_t stream)
{
  const float* rij         = (const float*)d_in[0];
  const int*   species     = (const int*)  d_in[1];
  const int*   first_atom  = (const int*)  d_in[2];
  const int*   second_atom = (const int*)  d_in[3];
  const float* Wr1 = (const float*)d_in[4];
  const float* br1 = (const float*)d_in[5];
  const float* Wr2 = (const float*)d_in[6];
  const float* br2 = (const float*)d_in[7];
  const float* Ws1 = (const float*)d_in[8];
  const float* bs1 = (const float*)d_in[9];
  const float* Ws2 = (const float*)d_in[10];
  const float* bs2 = (const float*)d_in[11];
  const float* Wa1 = (const float*)d_in[12];
  const float* ba1 = (const float*)d_in[13];
  const float* Wa2 = (const float*)d_in[14];
  const float* ba2 = (const float*)d_in[15];
  const float* Wa3 = (const float*)d_in[16];
  const float* ba3 = (const float*)d_in[17];
  float* ws  = (float*)d_ws;
  float* out = (float*)d_out;

  k_pre<<<(NK * 12) / 256, 256, 0, stream>>>(Wr1, br1, Wr2, br2, Ws1, bs1, Ws2, bs2, ws);
  k_scatter<<<NEDGES / 256, 256, 0, stream>>>(rij, first_atom, second_atom, species, ws);
  k_atom<<<NATOMS / 2, 128, 0, stream>>>(ws, Wa1, ba1, Wa2, ba2, Wa3, ba3, out);
}